// Round 7
// baseline (159.025 us; speedup 1.0000x reference)
//
#include <hip/hip_runtime.h>

// ---------------- problem constants ----------------
#define T_LEN   1048576
#define NPAD    1049600            // T_LEN + 2*512
#define NFRAMES 2049
#define BATCH   8
#define NJ      (BATCH * NFRAMES)  // 16392 total frames
#define NSEG    2050               // seg rows per batch
#define SMAX    (BATCH * NSEG - 1) // 16399
#define CUT     513
#define MROWS   1026
#define MPAD    1152               // 9 m-tiles of 128
#define OUT_BF  (CUT * NFRAMES)
#define JT      192                // j-tile
#define NJT     86                 // ceil(16392/192)
#define PAD_BLOCKS (BATCH * (NPAD / 8) / 256)   // 4100

typedef __attribute__((ext_vector_type(8))) short bf16x8_t;
typedef __attribute__((ext_vector_type(4))) float f32x4_t;

static __device__ __forceinline__ ushort f2bf(float f) {
    union { float f; unsigned u; } a;
    a.f = f;
    unsigned r = a.u + 0x7fffu + ((a.u >> 16) & 1u);
    return (ushort)(r >> 16);
}

static __device__ __forceinline__ void gl_lds16(const ushort* g, ushort* s) {
    __builtin_amdgcn_global_load_lds(
        (__attribute__((address_space(1))) void*)g,
        (__attribute__((address_space(3))) void*)s,
        16, 0, 0);
}

// ---------------- merged prep: reflect-pad + basis rearrange ----------------
__global__ void prep_kernel(const float* __restrict__ in, const float* __restrict__ fb,
                            ushort* __restrict__ xpad, ushort* __restrict__ A2) {
    const int tid = threadIdx.x;
    if (blockIdx.x < PAD_BLOCKS) {
        int g  = blockIdx.x * 256 + tid;
        int b  = g / (NPAD / 8);
        int c  = g - b * (NPAD / 8);
        int i0 = c * 8;
        const float* inb = in + (size_t)b * T_LEN;
        ushort o[8];
        if (i0 >= 512 && i0 + 7 < 512 + T_LEN) {
            const float4 v0 = *(const float4*)(inb + (i0 - 512));
            const float4 v1 = *(const float4*)(inb + (i0 - 512) + 4);
            o[0]=f2bf(v0.x); o[1]=f2bf(v0.y); o[2]=f2bf(v0.z); o[3]=f2bf(v0.w);
            o[4]=f2bf(v1.x); o[5]=f2bf(v1.y); o[6]=f2bf(v1.z); o[7]=f2bf(v1.w);
        } else {
            for (int t = 0; t < 8; ++t) {
                int i = i0 + t;
                int src = (i < 512) ? (512 - i)
                        : (i < 512 + T_LEN) ? (i - 512)
                        : (2 * T_LEN + 510 - i);
                o[t] = f2bf(inb[src]);
            }
        }
        *(ulonglong2*)(xpad + (size_t)b * NPAD + i0) = *(ulonglong2*)o;
    } else {
        int g  = (blockIdx.x - PAD_BLOCKS) * 256 + tid;
        int r  = g >> 8;
        int cq = (g & 255) * 4;
        ushort4 o;
        if (r < MROWS) {
            int f = r >> 1, h = r & 1;
            const float4 v = *(const float4*)(fb + (size_t)(f + h * CUT) * 1024 + cq);
            o = make_ushort4(f2bf(v.x), f2bf(v.y), f2bf(v.z), f2bf(v.w));
        } else {
            o = make_ushort4(0, 0, 0, 0);
        }
        *(ushort4*)(A2 + (size_t)r * 1024 + cq) = o;
    }
}

// ---- GEMM (hop-split, BK=64, XOR-swizzled LDS, XCD grid, 128M x 192J, 6 waves) ----
// C[m][j] = sum_{k'} A0[m][k']*seg(Sj)[k'] + A1[m][k']*seg(Sj+1)[k']
// LDS chunk c (16B) of row r holds global chunk c^(r&7) via per-lane source permute.
__global__ __launch_bounds__(384) void gemm_kernel(
        const ushort* __restrict__ A2, const ushort* __restrict__ xpad,
        float* __restrict__ out, const float* __restrict__ epsp) {
    __shared__ __align__(16) ushort ldsA0[128 * 64];   // 16 KB
    __shared__ __align__(16) ushort ldsA1[128 * 64];   // 16 KB
    __shared__ __align__(16) ushort ldsB [194 * 64];   // 24.25 KB

    // XCD swizzle: all 9 m-blocks of one j-tile share bid%8 -> same XCD L2
    const int bid = blockIdx.x;
    const int jt  = (bid / 72) * 8 + (bid & 7);
    const int mt  = (bid >> 3) % 9;
    if (jt >= NJT) return;                 // uniform early-exit (before any barrier)

    const int tid  = threadIdx.x;
    const int wave = tid >> 6, lane = tid & 63;
    const int quad = lane >> 4, l15 = lane & 15;
    const int m0 = mt * 128;
    const int j0 = jt * JT;
    const int wm = (wave & 1) * 64;        // 2 m-waves
    const int wj = (wave >> 1) * 64;       // 3 j-waves

    const int b0 = j0 / NFRAMES;
    const int S0 = j0 + b0;                // global seg index of LDS B row 0

    const int sr  = lane >> 3;             // staged row within 8-row group
    const int sc8 = ((lane & 7) ^ sr) * 8; // XOR-swizzled source chunk (elems)

    // A: issues q = wave + 6t (q < 16);  B: q = wave + 6t (t < 4, q < 24)
    int aoff[3], boff[4], boffx = 0;
    for (int t = 0; t < 3; ++t) {
        const int q = wave + 6 * t;
        aoff[t] = (q < 16) ? ((m0 + q * 8 + sr) * 1024 + sc8) : 0;
    }
    for (int t = 0; t < 4; ++t) {
        const int q = wave + 6 * t;
        int S = S0 + q * 8 + sr; if (S > SMAX) S = SMAX;
        int bb = S / NSEG, ss = S - bb * NSEG;
        boff[t] = bb * NPAD + ss * 512 + sc8;
    }
    {   // extra rows 192..193, staged by wave 5 lanes 0..15 (sr in {0,1})
        int S = S0 + 192 + sr; if (S > SMAX) S = SMAX;
        int bb = S / NSEG, ss = S - bb * NSEG;
        boffx = bb * NPAD + ss * 512 + sc8;
    }

    // per-lane B fragment base rows (handles batch-boundary shift)
    int rowb[4];
    for (int jx = 0; jx < 4; ++jx) {
        const int j = j0 + wj + jx * 16 + l15;
        rowb[jx] = wj + jx * 16 + l15 + (j / NFRAMES - b0);
    }

    f32x4_t acc[4][4] = {};

    for (int kt = 0; kt < 8; ++kt) {
        const int k0 = kt * 64;
        __syncthreads();
        #pragma unroll
        for (int t = 0; t < 3; ++t) {
            const int q = wave + 6 * t;
            if (q < 16) {
                gl_lds16(A2 + aoff[t] + k0,       &ldsA0[q * 512]);
                gl_lds16(A2 + aoff[t] + 512 + k0, &ldsA1[q * 512]);
            }
        }
        #pragma unroll
        for (int t = 0; t < 4; ++t)
            gl_lds16(xpad + boff[t] + k0, &ldsB[(wave + 6 * t) * 512]);
        if (wave == 5 && lane < 16) gl_lds16(xpad + boffx + k0, &ldsB[24 * 512]);
        __syncthreads();
        for (int kk = 0; kk < 2; ++kk) {
            const int cb = kk * 4 + quad;      // within-window chunk 0..7
            bf16x8_t a0[4], a1[4], bf0[4], bf1[4];
            const int asw = (cb ^ (l15 & 7)) * 8;
            for (int i = 0; i < 4; ++i) {
                const int ro = (wm + i * 16 + l15) * 64;
                a0[i] = *(const bf16x8_t*)&ldsA0[ro + asw];
                a1[i] = *(const bf16x8_t*)&ldsA1[ro + asw];
            }
            for (int jx = 0; jx < 4; ++jx) {
                const int r0 = rowb[jx];
                const int r1 = r0 + 1;
                bf0[jx] = *(const bf16x8_t*)&ldsB[r0 * 64 + ((cb ^ (r0 & 7)) * 8)];
                bf1[jx] = *(const bf16x8_t*)&ldsB[r1 * 64 + ((cb ^ (r1 & 7)) * 8)];
            }
            for (int i = 0; i < 4; ++i)
                for (int jx = 0; jx < 4; ++jx) {
                    acc[i][jx] = __builtin_amdgcn_mfma_f32_16x16x32_bf16(
                        a0[i], bf0[jx], acc[i][jx], 0, 0, 0);
                    acc[i][jx] = __builtin_amdgcn_mfma_f32_16x16x32_bf16(
                        a1[i], bf1[jx], acc[i][jx], 0, 0, 0);
                }
        }
    }

    // epilogue: C/D layout col=lane&15 (-> j), row=quad*4+reg (-> M)
    const float eps = *epsp;
    for (int tj = 0; tj < 4; ++tj) {
        const int j = j0 + wj + tj * 16 + l15;
        if (j >= NJ) continue;
        const int b = j / NFRAMES;
        const int n = j - b * NFRAMES;
        float* ob = out + (size_t)b * OUT_BF + n;
        for (int ti = 0; ti < 4; ++ti) {
            const int M  = m0 + wm + ti * 16 + quad * 4;
            const int f0 = M >> 1;
            f32x4_t a = acc[ti][tj];
            if (f0 < CUT)
                ob[(size_t)f0 * NFRAMES] = sqrtf(a.x * a.x + a.y * a.y + eps);
            if (f0 + 1 < CUT)
                ob[(size_t)(f0 + 1) * NFRAMES] = sqrtf(a.z * a.z + a.w * a.w + eps);
        }
    }
}

extern "C" void kernel_launch(void* const* d_in, const int* in_sizes, int n_in,
                              void* d_out, int out_size, void* d_ws, size_t ws_size,
                              hipStream_t stream) {
    const float* in   = (const float*)d_in[0];
    const float* fb   = (const float*)d_in[1];
    const float* epsp = (const float*)d_in[2];
    float* out = (float*)d_out;

    ushort* A2   = (ushort*)d_ws;                                    // 1152*1024*2B
    ushort* xpad = (ushort*)((char*)d_ws + (size_t)MPAD * 1024 * 2); // 8*NPAD*2B

    prep_kernel<<<dim3(PAD_BLOCKS + MPAD), dim3(256), 0, stream>>>(in, fb, xpad, A2);
    // grid: 11 groups x (8 j-tiles x 9 m-tiles); blocks with jt>=86 early-exit
    gemm_kernel<<<dim3(11 * 72), dim3(384), 0, stream>>>(A2, xpad, out, epsp);
}

// Round 8
// 116.331 us; speedup vs baseline: 1.3670x; 1.3670x over previous
//
#include <hip/hip_runtime.h>

// ---------------- problem constants ----------------
#define T_LEN   1048576
#define NPAD    1049600            // T_LEN + 2*512 (bytes in i8 xpad, elems too)
#define NFRAMES 2049
#define BATCH   8
#define NJ      (BATCH * NFRAMES)  // 16392 total frames
#define NSEG    2050               // seg rows per batch
#define SMAX    (BATCH * NSEG - 1) // 16399
#define CUT     513
#define MROWS   1026
#define MPAD    1152               // 9 m-tiles of 128
#define OUT_BF  (CUT * NFRAMES)
#define NJT     129                // j-tiles of 128
#define PAD_BLOCKS (BATCH * (NPAD / 16) / 256)  // 2050
#define SB      28.222223f         // B scale = 127/4.5
#define INVS    (4.5f / 16129.f)   // 1/(127*SB)

typedef __attribute__((ext_vector_type(4))) int i32x4_t;

static __device__ __forceinline__ void gl_lds16(const char* g, char* s) {
    __builtin_amdgcn_global_load_lds(
        (__attribute__((address_space(1))) void*)g,
        (__attribute__((address_space(3))) void*)s,
        16, 0, 0);
}

static __device__ __forceinline__ char q127(float v, float scale) {
    return (char)(int)rintf(fminf(fmaxf(v * scale, -127.f), 127.f));
}

// ---------------- merged prep: reflect-pad + basis rearrange (both -> i8) ----------------
__global__ void prep_kernel(const float* __restrict__ in, const float* __restrict__ fb,
                            char* __restrict__ xpad, char* __restrict__ A2) {
    const int tid = threadIdx.x;
    if (blockIdx.x < PAD_BLOCKS) {
        int g  = blockIdx.x * 256 + tid;       // 16-elem chunk
        int b  = g / (NPAD / 16);
        int c  = g - b * (NPAD / 16);
        int i0 = c * 16;
        const float* inb = in + (size_t)b * T_LEN;
        union { char c[16]; ulonglong2 v; } u;
        if (i0 >= 512 && i0 + 15 < 512 + T_LEN) {
            #pragma unroll
            for (int t = 0; t < 16; t += 4) {
                const float4 v = *(const float4*)(inb + (i0 - 512) + t);
                u.c[t + 0] = q127(v.x, SB); u.c[t + 1] = q127(v.y, SB);
                u.c[t + 2] = q127(v.z, SB); u.c[t + 3] = q127(v.w, SB);
            }
        } else {
            for (int t = 0; t < 16; ++t) {
                int i = i0 + t;
                int src = (i < 512) ? (512 - i)
                        : (i < 512 + T_LEN) ? (i - 512)
                        : (2 * T_LEN + 510 - i);
                u.c[t] = q127(inb[src], SB);
            }
        }
        *(ulonglong2*)(xpad + (size_t)b * NPAD + i0) = u.v;
    } else {
        int g  = (blockIdx.x - PAD_BLOCKS) * 256 + tid;
        int r  = g >> 8;
        int cq = (g & 255) * 4;
        union { char c[4]; unsigned u; } o;
        if (r < MROWS) {
            int f = r >> 1, h = r & 1;
            const float4 v = *(const float4*)(fb + (size_t)(f + h * CUT) * 1024 + cq);
            o.c[0] = q127(v.x, 127.f); o.c[1] = q127(v.y, 127.f);
            o.c[2] = q127(v.z, 127.f); o.c[3] = q127(v.w, 127.f);
        } else {
            o.u = 0;
        }
        *(unsigned*)(A2 + (size_t)r * 1024 + cq) = o.u;
    }
}

// ---- GEMM i8 (hop-split, BK=128 bytes, XOR-swizzled LDS, XCD grid, r5 geometry) ----
// C[m][j] = sum_{k'<512} A0[m][k']*seg(Sj)[k'] + A1[m][k']*seg(Sj+1)[k']  (i32 exact)
// LDS 16B chunk c of row r holds global chunk c^(r&7) via per-lane source permute.
__global__ __launch_bounds__(256) void gemm_kernel(
        const char* __restrict__ A2, const char* __restrict__ xpad,
        float* __restrict__ out, const float* __restrict__ epsp) {
    __shared__ __align__(16) char ldsA0[128 * 128];   // 16 KB
    __shared__ __align__(16) char ldsA1[128 * 128];   // 16 KB
    __shared__ __align__(16) char ldsB [136 * 128];   // 17 KB

    // XCD swizzle: all 9 m-blocks of one j-tile share bid%8 -> same XCD L2
    const int bid = blockIdx.x;
    const int jt  = (bid / 72) * 8 + (bid & 7);
    const int mt  = (bid >> 3) % 9;
    if (jt >= NJT) return;                 // uniform early-exit (before any barrier)

    const int tid  = threadIdx.x;
    const int wave = tid >> 6, lane = tid & 63;
    const int quad = lane >> 4, l15 = lane & 15;
    const int m0 = mt * 128;
    const int j0 = jt * 128;
    const int wm = (wave >> 1) * 64;
    const int wj = (wave & 1) * 64;

    const int b0 = j0 / NFRAMES;
    const int S0 = j0 + b0;                // global seg index of LDS B row 0

    const int sr   = lane >> 3;            // staged row within 8-row group
    const int sc16 = ((lane & 7) ^ sr) * 16; // XOR-swizzled source chunk (bytes)

    int aoff[4], boff[4], boffx = 0;
    for (int t = 0; t < 4; ++t) {
        const int r = (wave * 4 + t) * 8 + sr;
        aoff[t] = (m0 + r) * 1024 + sc16;
        int S = S0 + r; if (S > SMAX) S = SMAX;
        int bb = S / NSEG, ss = S - bb * NSEG;
        boff[t] = bb * NPAD + ss * 512 + sc16;
    }
    {
        int S = S0 + 128 + sr; if (S > SMAX) S = SMAX;
        int bb = S / NSEG, ss = S - bb * NSEG;
        boffx = bb * NPAD + ss * 512 + sc16;
    }

    // per-lane B fragment base rows (handles batch-boundary shift)
    int rowb[4];
    for (int jx = 0; jx < 4; ++jx) {
        const int j = j0 + wj + jx * 16 + l15;
        rowb[jx] = wj + jx * 16 + l15 + (j / NFRAMES - b0);
    }

    i32x4_t acc[4][4] = {};

    for (int kt = 0; kt < 4; ++kt) {
        const int k0 = kt * 128;           // byte offset into k'
        __syncthreads();
        for (int t = 0; t < 4; ++t) {
            const int q = wave * 4 + t;
            gl_lds16(A2 + aoff[t] + k0,        &ldsA0[q * 1024]);
            gl_lds16(A2 + aoff[t] + 512 + k0,  &ldsA1[q * 1024]);
            gl_lds16(xpad + boff[t] + k0,      &ldsB [q * 1024]);
        }
        if (wave == 0) gl_lds16(xpad + boffx + k0, &ldsB[16 * 1024]);
        __syncthreads();
        for (int kk = 0; kk < 2; ++kk) {
            const int cb = kk * 4 + quad;  // within-interval 16B chunk 0..7
            i32x4_t a0[4], a1[4], bf0[4], bf1[4];
            const int asw = (cb ^ (l15 & 7)) * 16;
            for (int i = 0; i < 4; ++i) {
                const int ro = (wm + i * 16 + l15) * 128;
                a0[i] = *(const i32x4_t*)&ldsA0[ro + asw];
                a1[i] = *(const i32x4_t*)&ldsA1[ro + asw];
            }
            for (int jx = 0; jx < 4; ++jx) {
                const int r0 = rowb[jx];
                const int r1 = r0 + 1;
                bf0[jx] = *(const i32x4_t*)&ldsB[r0 * 128 + ((cb ^ (r0 & 7)) * 16)];
                bf1[jx] = *(const i32x4_t*)&ldsB[r1 * 128 + ((cb ^ (r1 & 7)) * 16)];
            }
            for (int i = 0; i < 4; ++i)
                for (int jx = 0; jx < 4; ++jx) {
                    acc[i][jx] = __builtin_amdgcn_mfma_i32_16x16x64_i8(
                        a0[i], bf0[jx], acc[i][jx], 0, 0, 0);
                    acc[i][jx] = __builtin_amdgcn_mfma_i32_16x16x64_i8(
                        a1[i], bf1[jx], acc[i][jx], 0, 0, 0);
                }
        }
    }

    // epilogue: C/D layout col=lane&15 (-> j), row=quad*4+reg (-> M)
    const float eps = *epsp;
    for (int tj = 0; tj < 4; ++tj) {
        const int j = j0 + wj + tj * 16 + l15;
        if (j >= NJ) continue;
        const int b = j / NFRAMES;
        const int n = j - b * NFRAMES;
        float* ob = out + (size_t)b * OUT_BF + n;
        for (int ti = 0; ti < 4; ++ti) {
            const int M  = m0 + wm + ti * 16 + quad * 4;
            const int f0 = M >> 1;
            i32x4_t c = acc[ti][tj];
            float rx = c.x * INVS, ry = c.y * INVS;
            float rz = c.z * INVS, rw = c.w * INVS;
            if (f0 < CUT)
                ob[(size_t)f0 * NFRAMES] = sqrtf(rx * rx + ry * ry + eps);
            if (f0 + 1 < CUT)
                ob[(size_t)(f0 + 1) * NFRAMES] = sqrtf(rz * rz + rw * rw + eps);
        }
    }
}

extern "C" void kernel_launch(void* const* d_in, const int* in_sizes, int n_in,
                              void* d_out, int out_size, void* d_ws, size_t ws_size,
                              hipStream_t stream) {
    const float* in   = (const float*)d_in[0];
    const float* fb   = (const float*)d_in[1];
    const float* epsp = (const float*)d_in[2];
    float* out = (float*)d_out;

    char* A2   = (char*)d_ws;                               // MPAD*1024 B = 1.18 MB
    char* xpad = (char*)d_ws + (size_t)MPAD * 1024;         // 8*NPAD B = 8.4 MB

    prep_kernel<<<dim3(PAD_BLOCKS + MPAD), dim3(256), 0, stream>>>(in, fb, xpad, A2);
    // grid: 17 groups x (8 j-tiles x 9 m-tiles); blocks with jt>=129 early-exit
    gemm_kernel<<<dim3(17 * 72), dim3(256), 0, stream>>>(A2, xpad, out, epsp);
}